// Round 8
// baseline (391.016 us; speedup 1.0000x reference)
//
#include <hip/hip_runtime.h>

// Problem constants (fixed by the reference).
static constexpr int kB  = 2;
static constexpr int kL  = 4096;   // source sequence length
static constexpr int kD  = 1024;
static constexpr int kH  = 16;
static constexpr int kDH = 64;
static constexpr int kM  = 256;
static constexpr int kN  = kB * kL;              // 8192 deduplicated rows
static constexpr float kScale    = 0.35355339059327373f;  // DH^-0.25
static constexpr float kInvSqrtM = 0.0625f;               // M^-0.5
static constexpr float kEps   = 1e-6f;
static constexpr float kLnEps = 1e-5f;

typedef __attribute__((ext_vector_type(8))) short short8;   // 8 bf16 (4 VGPRs)
typedef __attribute__((ext_vector_type(4))) float f32x4;

__device__ __forceinline__ float bf2f(unsigned short h) {
  union { unsigned int u; float f; } c;
  c.u = ((unsigned int)h) << 16;
  return c.f;
}
__device__ __forceinline__ unsigned short f2bf(float f) {
  union { float f; unsigned int u; } c;
  c.f = f;
  unsigned int u = c.u;
  u += 0x7fffu + ((u >> 16) & 1u);   // round-to-nearest-even
  return (unsigned short)(u >> 16);
}

// async global->LDS, 16 B per lane; LDS dest = wave-uniform base + lane*16.
__device__ __forceinline__ void gload_lds16(const unsigned short* g,
                                            unsigned short* l) {
  __builtin_amdgcn_global_load_lds(
      (const __attribute__((address_space(1))) unsigned int*)g,
      (__attribute__((address_space(3))) unsigned int*)l, 16, 0, 0);
}

// ---------------------------------------------------------------------------
// casts
// ---------------------------------------------------------------------------
__global__ __launch_bounds__(256) void cast_bf16_kernel(
    const float* __restrict__ in, unsigned short* __restrict__ out)
{
  const int i = blockIdx.x * 256 + threadIdx.x;
  float4 v = ((const float4*)in)[i];
  ushort4 o;
  o.x = f2bf(v.x); o.y = f2bf(v.y); o.z = f2bf(v.z); o.w = f2bf(v.w);
  ((ushort4*)out)[i] = o;
}

// WT[n][k] = bf16(W[k][n]), 1024x1024.
__global__ __launch_bounds__(256) void transpose_cast_kernel(
    const float* __restrict__ W, unsigned short* __restrict__ WT)
{
  __shared__ float tile[32][33];
  const int n0 = blockIdx.x * 32, k0 = blockIdx.y * 32;
  const int t = threadIdx.x, kk = t >> 5, nn = t & 31;
#pragma unroll
  for (int i = 0; i < 4; ++i)
    tile[kk + i * 8][nn] = W[(size_t)(k0 + kk + i * 8) * kD + n0 + nn];
  __syncthreads();
#pragma unroll
  for (int i = 0; i < 4; ++i)
    WT[(size_t)(n0 + kk + i * 8) * kD + k0 + nn] = f2bf(tile[nn][kk + i * 8]);
}

// ---------------------------------------------------------------------------
// MFMA GEMM (m97-style): C[N,1024] = alpha * A[N,1024] @ B, BT transposed.
// 128x128 tile, BK=32, unpadded LDS (64 B rows), global_load_lds width-16
// staging, 4 waves, 4x4 subtiles.
// OUT_MODE: 0 = f32 row-major, 1 = bf16 row-major,
//           2 = bf16 per-head transposed VT[b,h,d,l] (for the kv GEMM).
// ---------------------------------------------------------------------------
template <int OUT_MODE>
__global__ __launch_bounds__(256) void gemm_mfma(
    const unsigned short* __restrict__ A, const unsigned short* __restrict__ BT,
    void* __restrict__ Cout, float alpha)
{
  __shared__ unsigned short As[128 * 32];   // 8 KB, unpadded (m97 layout)
  __shared__ unsigned short Bs[128 * 32];
  __shared__ unsigned short Tbuf[OUT_MODE == 2 ? 64 * 136 : 1];
  const int tid = threadIdx.x, lane = tid & 63, w = tid >> 6;
  const int q = lane >> 4, c = lane & 15;
  const int wr = (w >> 1) * 64, wc = (w & 1) * 64;
  const int row0 = blockIdx.y * 128, col0 = blockIdx.x * 128;
  const int lrow = lane >> 2, lcol = (lane & 3) * 8;   // async-load lane map

  f32x4 acc[4][4];
#pragma unroll
  for (int i = 0; i < 4; ++i)
#pragma unroll
    for (int j = 0; j < 4; ++j) acc[i][j] = (f32x4)0.f;

  for (int k0 = 0; k0 < kD; k0 += 32) {
    // stage: each wave issues 2 A + 2 B async 1 KB loads (16 rows each)
#pragma unroll
    for (int i = 0; i < 2; ++i) {
      const int r0 = w * 32 + i * 16;
      gload_lds16(&A[(size_t)(row0 + r0 + lrow) * kD + k0 + lcol], &As[r0 * 32]);
      gload_lds16(&BT[(size_t)(col0 + r0 + lrow) * kD + k0 + lcol], &Bs[r0 * 32]);
    }
    __syncthreads();   // drains vmcnt(0) before barrier
    short8 av[4], bv[4];
#pragma unroll
    for (int i = 0; i < 4; ++i)
      av[i] = *(const short8*)&As[(wr + i * 16 + c) * 32 + q * 8];
#pragma unroll
    for (int j = 0; j < 4; ++j)
      bv[j] = *(const short8*)&Bs[(wc + j * 16 + c) * 32 + q * 8];
#pragma unroll
    for (int i = 0; i < 4; ++i)
#pragma unroll
      for (int j = 0; j < 4; ++j)
        acc[i][j] = __builtin_amdgcn_mfma_f32_16x16x32_bf16(
            av[i], bv[j], acc[i][j], 0, 0, 0);
    __syncthreads();
  }

  if (OUT_MODE != 2) {
#pragma unroll
    for (int i = 0; i < 4; ++i)
#pragma unroll
      for (int j = 0; j < 4; ++j)
#pragma unroll
        for (int r = 0; r < 4; ++r) {
          const int row = row0 + wr + i * 16 + q * 4 + r;
          const int col = col0 + wc + j * 16 + c;
          const float v = alpha * acc[i][j][r];
          if (OUT_MODE == 1)
            ((unsigned short*)Cout)[(size_t)row * kD + col] = f2bf(v);
          else
            ((float*)Cout)[(size_t)row * kD + col] = v;
        }
  } else {
    // Transposed per-head store: VT[(b*16+h)*64 + d][l], via LDS transpose.
    const int bq = row0 >> 12, l0 = row0 & 4095;
#pragma unroll
    for (int hh = 0; hh < 2; ++hh) {
      if ((w & 1) == hh) {
#pragma unroll
        for (int i = 0; i < 4; ++i)
#pragma unroll
          for (int j = 0; j < 4; ++j) {
            ushort4 o;
            o.x = f2bf(acc[i][j][0]); o.y = f2bf(acc[i][j][1]);
            o.z = f2bf(acc[i][j][2]); o.w = f2bf(acc[i][j][3]);
            *(ushort4*)&Tbuf[(j * 16 + c) * 136 + wr + i * 16 + q * 4] = o;
          }
      }
      __syncthreads();
      {
        const int dl = tid >> 2, seg = tid & 3;
        const size_t dst =
            ((size_t)(bq * 1024 + col0 + hh * 64 + dl)) * (size_t)kL +
            l0 + seg * 32;
        uint4* gp = (uint4*)((unsigned short*)Cout + dst);
        const unsigned short* sp = &Tbuf[dl * 136 + seg * 32];
#pragma unroll
        for (int u = 0; u < 4; ++u) gp[u] = *(const uint4*)&sp[u * 8];
      }
      __syncthreads();
    }
  }
}

// ---------------------------------------------------------------------------
// FAVOR features via MFMA — 64-row l-tiles for occupancy/latency.
// Per block: (b,h), 64-row l-tile. dash[64x256] = U_tile[64x64] @ proj[h]^T;
// proj fragments read straight from global (L2-hot).
// TRANS=0: store F row-major [bh][l][m] (QF), coalesced via LDS chunks.
// TRANS=1: store F transposed [bh][m][l] (KFT), coalesced via LDS chunks.
// grid (32 bh, 64 l-tiles), 256 threads (wave w owns rows w*16..w*16+15).
// ---------------------------------------------------------------------------
template <int TRANS>
__global__ __launch_bounds__(256) void favor_mfma(
    const unsigned short* __restrict__ U, const unsigned short* __restrict__ projb,
    unsigned short* __restrict__ F)
{
  __shared__ unsigned short Us[64 * 72];                        // 9 KB
  __shared__ unsigned short Tbuf[TRANS ? 128 * 72 : 64 * 136];  // ~18 KB
  __shared__ float diagp[4 * 64];
  __shared__ float diag[64];
  const int bh = blockIdx.x, b = bh >> 4, h = bh & 15;
  const int l0 = blockIdx.y * 64;
  const int tid = threadIdx.x, lane = tid & 63, w = tid >> 6;
  const int q = lane >> 4, c = lane & 15;
  const int wr = w * 16;

  // stage U tile: 64 rows x 64 bf16 (512 ushort8 -> 2 per thread)
#pragma unroll
  for (int it = 0; it < 2; ++it) {
    int idx = it * 256 + tid;
    int row = idx >> 3, col8 = idx & 7;
    *(uint4*)&Us[row * 72 + col8 * 8] =
        *(const uint4*)&U[((size_t)(b * kL + l0 + row)) * kD + h * kDH + col8 * 8];
  }
  __syncthreads();

  // diag partials: thread -> (row = tid&63, quarter = tid>>6), 16 d each
  {
    int row = tid & 63, quar = tid >> 6;
    const unsigned short* ur = &Us[row * 72 + quar * 16];
    float s = 0.f;
#pragma unroll
    for (int d8 = 0; d8 < 2; ++d8) {
      uint4 raw = *(const uint4*)&ur[d8 * 8];
      const unsigned short* us = (const unsigned short*)&raw;
#pragma unroll
      for (int jj = 0; jj < 8; ++jj) { float v = bf2f(us[jj]); s = fmaf(v, v, s); }
    }
    diagp[quar * 64 + row] = s;
  }

  f32x4 acc[16];
#pragma unroll
  for (int j = 0; j < 16; ++j) acc[j] = (f32x4)0.f;

#pragma unroll
  for (int ks = 0; ks < 2; ++ks) {
    short8 av = *(const short8*)&Us[(wr + c) * 72 + ks * 32 + q * 8];
#pragma unroll
    for (int jb = 0; jb < 2; ++jb) {
      short8 bv[8];
#pragma unroll
      for (int jl = 0; jl < 8; ++jl)
        bv[jl] = *(const short8*)&projb[
            ((size_t)(h * kM + (jb * 8 + jl) * 16 + c)) * kDH + ks * 32 + q * 8];
#pragma unroll
      for (int jl = 0; jl < 8; ++jl)
        acc[jb * 8 + jl] = __builtin_amdgcn_mfma_f32_16x16x32_bf16(
            av, bv[jl], acc[jb * 8 + jl], 0, 0, 0);
    }
  }

  __syncthreads();
  if (tid < 64)
    diag[tid] = 0.5f * ((diagp[tid] + diagp[64 + tid]) +
                        (diagp[128 + tid] + diagp[192 + tid]));
  __syncthreads();

  // exp epilogue: acc <- exp(dash - diag - rowmax) * M^-0.5
#pragma unroll
  for (int r = 0; r < 4; ++r) {
    const int lrow = wr + q * 4 + r;
    float mx = -3.4e38f;
#pragma unroll
    for (int j = 0; j < 16; ++j) mx = fmaxf(mx, acc[j][r]);
    mx = fmaxf(mx, __shfl_xor(mx, 1, 64));
    mx = fmaxf(mx, __shfl_xor(mx, 2, 64));
    mx = fmaxf(mx, __shfl_xor(mx, 4, 64));
    mx = fmaxf(mx, __shfl_xor(mx, 8, 64));
    const float base = diag[lrow] + mx;
#pragma unroll
    for (int j = 0; j < 16; ++j)
      acc[j][r] = __expf(acc[j][r] - base) * kInvSqrtM;
  }

  if (TRANS == 0) {
    // Row-major QF via LDS: two 128-m chunks, Tbuf[64 l][136].
#pragma unroll
    for (int mc = 0; mc < 2; ++mc) {
      if (mc) __syncthreads();
#pragma unroll
      for (int jl = 0; jl < 8; ++jl) {
        const int j = mc * 8 + jl;
#pragma unroll
        for (int r = 0; r < 4; ++r)
          Tbuf[(wr + q * 4 + r) * 136 + jl * 16 + c] = f2bf(acc[j][r]);
      }
      __syncthreads();
#pragma unroll
      for (int it = 0; it < 4; ++it) {
        int idx = it * 256 + tid;          // 1024 ushort8 = 64 l x 16
        int row = idx >> 4, m8 = idx & 15;
        *(uint4*)&F[((size_t)bh * kL + (l0 + row)) * kM + mc * 128 + m8 * 8] =
            *(const uint4*)&Tbuf[row * 136 + m8 * 8];
      }
    }
  } else {
    // Transposed KFT via LDS: two 128-m chunks, Tbuf[128 m][72].
#pragma unroll
    for (int mc = 0; mc < 2; ++mc) {
      if (mc) __syncthreads();
#pragma unroll
      for (int jl = 0; jl < 8; ++jl) {
        const int j = mc * 8 + jl;
        ushort4 o;
        o.x = f2bf(acc[j][0]); o.y = f2bf(acc[j][1]);
        o.z = f2bf(acc[j][2]); o.w = f2bf(acc[j][3]);
        *(ushort4*)&Tbuf[(jl * 16 + c) * 72 + wr + q * 4] = o;
      }
      __syncthreads();
#pragma unroll
      for (int it = 0; it < 4; ++it) {
        int idx = it * 256 + tid;          // 1024 ushort8 = 128 m x 8
        int m = idx >> 3, l8 = idx & 7;
        *(uint4*)&F[((size_t)(bh * kM + mc * 128 + m)) * (size_t)kL +
                    l0 + l8 * 8] = *(const uint4*)&Tbuf[m * 72 + l8 * 8];
      }
    }
  }
}

// ---------------------------------------------------------------------------
// kv via MFMA: per (bh, mtile, split): C[128 m][64 d] = KFT tile @ VT tile^T
// over 512 l. ksum[m] from the A-fragments (register + shfl).
// ---------------------------------------------------------------------------
__global__ __launch_bounds__(256) void kv_mfma(
    const unsigned short* __restrict__ KFT, const unsigned short* __restrict__ VT,
    float* __restrict__ KVP, float* __restrict__ KSP)
{
  __shared__ unsigned short As[128 * 40];
  __shared__ unsigned short Bs[64 * 40];
  const int bh = blockIdx.x, mtile = blockIdx.y, split = blockIdx.z;
  const int tid = threadIdx.x, lane = tid & 63, w = tid >> 6;
  const int q = lane >> 4, c = lane & 15;
  const int l0 = split * 512;
  const unsigned short* Abase = KFT + ((size_t)(bh * kM + mtile * 128)) * kL + l0;
  const unsigned short* Bbase = VT + ((size_t)(bh * kDH)) * kL + l0;

  f32x4 acc[2][4];
#pragma unroll
  for (int i = 0; i < 2; ++i)
#pragma unroll
    for (int j = 0; j < 4; ++j) acc[i][j] = (f32x4)0.f;
  float ksr[2] = {0.f, 0.f};

  for (int k0 = 0; k0 < 512; k0 += 32) {
    __syncthreads();
#pragma unroll
    for (int it = 0; it < 2; ++it) {
      int idx = it * 256 + tid;               // 512 uint4 for A
      int row = idx >> 2, c8 = (idx & 3) * 8;
      *(uint4*)&As[row * 40 + c8] = *(const uint4*)&Abase[(size_t)row * kL + k0 + c8];
    }
    {
      int row = tid >> 2, c8 = (tid & 3) * 8;  // 256 uint4 for B
      *(uint4*)&Bs[row * 40 + c8] = *(const uint4*)&Bbase[(size_t)row * kL + k0 + c8];
    }
    __syncthreads();
    short8 av[2], bv[4];
#pragma unroll
    for (int i = 0; i < 2; ++i) {
      av[i] = *(const short8*)&As[(w * 32 + i * 16 + c) * 40 + q * 8];
#pragma unroll
      for (int e = 0; e < 8; ++e) ksr[i] += bf2f((unsigned short)av[i][e]);
    }
#pragma unroll
    for (int j = 0; j < 4; ++j)
      bv[j] = *(const short8*)&Bs[(j * 16 + c) * 40 + q * 8];
#pragma unroll
    for (int i = 0; i < 2; ++i)
#pragma unroll
      for (int j = 0; j < 4; ++j)
        acc[i][j] = __builtin_amdgcn_mfma_f32_16x16x32_bf16(
            av[i], bv[j], acc[i][j], 0, 0, 0);
  }

  const int blk = (bh * 2 + mtile) * 8 + split;
  float* op = KVP + (size_t)blk * (128 * 64);
#pragma unroll
  for (int i = 0; i < 2; ++i)
#pragma unroll
    for (int j = 0; j < 4; ++j)
#pragma unroll
      for (int r = 0; r < 4; ++r)
        op[(w * 32 + i * 16 + q * 4 + r) * 64 + j * 16 + c] = acc[i][j][r];

#pragma unroll
  for (int i = 0; i < 2; ++i) {
    float s = ksr[i];
    s += __shfl_xor(s, 16, 64);
    s += __shfl_xor(s, 32, 64);
    if (q == 0) KSP[blk * 128 + w * 32 + i * 16 + c] = s;
  }
}

// Reduce 8 splits -> KVT' bf16 [bh][80][256]: rows 0..63 = kv^T[d][m],
// row 64 = ksum[m], rows 65..79 = 0 (pad n-tile for the MFMA attn).
__global__ __launch_bounds__(256) void kv_reduce_kernel(
    const float* __restrict__ KVP, const float* __restrict__ KSP,
    unsigned short* __restrict__ KVT)
{
  const int blk = blockIdx.x;            // 32*80
  const int bh = blk / 80, n = blk - bh * 80;
  const int t = threadIdx.x;             // m
  const int mt = t >> 7, ml = t & 127;
  float s = 0.f;
  if (n < 64) {
#pragma unroll
    for (int sp = 0; sp < 8; ++sp)
      s += KVP[((size_t)((bh * 2 + mt) * 8 + sp)) * (128 * 64) + ml * 64 + n];
  } else if (n == 64) {
#pragma unroll
    for (int sp = 0; sp < 8; ++sp)
      s += KSP[((bh * 2 + mt) * 8 + sp) * 128 + ml];
  }
  KVT[(size_t)bh * (80 * kM) + n * kM + t] = f2bf(s);
}

// ---------------------------------------------------------------------------
// MFMA attention read-out: per (b,h): C = QF[4096x256] @ KVT'^T, n-tile 4
// carries ksum -> denominator. Writes bf16 ATTN [N][1024].
// ---------------------------------------------------------------------------
__global__ __launch_bounds__(256) void attn_mfma(
    const unsigned short* __restrict__ QF, const unsigned short* __restrict__ KVT,
    unsigned short* __restrict__ ATTN)
{
  __shared__ unsigned short kvs[80 * 264];   // padded stride 264
  __shared__ unsigned short qs[128 * 40];
  const int bh = blockIdx.x, b = bh >> 4, h = bh & 15;
  const int l0 = blockIdx.y * 128;
  const int tid = threadIdx.x, lane = tid & 63, w = tid >> 6;
  const int q = lane >> 4, c = lane & 15;
  const int trow = tid >> 2, tc8 = (tid & 3) * 8;

#pragma unroll
  for (int it = 0; it < 20; ++it) {
    int idx4 = it * 256 + tid;           // ushort4 units, 5120 total
    int row = idx4 >> 6, col4 = idx4 & 63;
    *(ushort4*)&kvs[row * 264 + col4 * 4] =
        *(const ushort4*)&KVT[(size_t)bh * (80 * kM) + row * kM + col4 * 4];
  }

  f32x4 acc[2][5];
#pragma unroll
  for (int i = 0; i < 2; ++i)
#pragma unroll
    for (int j = 0; j < 5; ++j) acc[i][j] = (f32x4)0.f;

  for (int kk = 0; kk < 8; ++kk) {
    __syncthreads();
#pragma unroll
    for (int i = 0; i < 2; ++i)
      *(uint4*)&qs[(trow + 64 * i) * 40 + tc8] =
          *(const uint4*)&QF[((size_t)bh * kL + (l0 + trow + 64 * i)) * kM +
                             kk * 32 + tc8];
    __syncthreads();
    short8 bv[5];
#pragma unroll
    for (int j = 0; j < 5; ++j)
      bv[j] = *(const short8*)&kvs[(j * 16 + c) * 264 + kk * 32 + q * 8];
#pragma unroll
    for (int i = 0; i < 2; ++i) {
      short8 av = *(const short8*)&qs[(w * 32 + i * 16 + c) * 40 + q * 8];
#pragma unroll
      for (int j = 0; j < 5; ++j)
        acc[i][j] = __builtin_amdgcn_mfma_f32_16x16x32_bf16(
            av, bv[j], acc[i][j], 0, 0, 0);
    }
  }

#pragma unroll
  for (int i = 0; i < 2; ++i)
#pragma unroll
    for (int r = 0; r < 4; ++r) {
      float den = __shfl(acc[i][4][r], (lane & 48));
      float z = 1.f / (den + kEps);
      const int row = l0 + w * 32 + i * 16 + q * 4 + r;
      const size_t base = ((size_t)(b * kL + row)) * kD + h * kDH;
#pragma unroll
      for (int j = 0; j < 4; ++j)
        ATTN[base + j * 16 + c] = f2bf(acc[i][j][r] * z);
    }
}

// ---------------------------------------------------------------------------
// GELU (exact) + LayerNorm + 2x nearest-neighbor duplicate write.
// ---------------------------------------------------------------------------
__global__ __launch_bounds__(256) void gelu_ln_kernel(
    const float* __restrict__ Y, const float* __restrict__ lng,
    const float* __restrict__ lnb, float* __restrict__ OUT)
{
  __shared__ float r1[4], r2[4];
  const int n = blockIdx.x;
  const int tid = threadIdx.x, lane = tid & 63, w = tid >> 6;

  float4 y4 = ((const float4*)(Y + (size_t)n * kD))[tid];
  float g0 = 0.5f * y4.x * (1.f + erff(y4.x * 0.70710678118654752f));
  float g1 = 0.5f * y4.y * (1.f + erff(y4.y * 0.70710678118654752f));
  float g2 = 0.5f * y4.z * (1.f + erff(y4.z * 0.70710678118654752f));
  float g3 = 0.5f * y4.w * (1.f + erff(y4.w * 0.70710678118654752f));

  float s  = (g0 + g1) + (g2 + g3);
  float ss = (g0 * g0 + g1 * g1) + (g2 * g2 + g3 * g3);
#pragma unroll
  for (int off = 32; off; off >>= 1) {
    s  += __shfl_xor(s, off, 64);
    ss += __shfl_xor(ss, off, 64);
  }
  if (lane == 0) { r1[w] = s; r2[w] = ss; }
  __syncthreads();
  s  = (r1[0] + r1[1]) + (r1[2] + r1[3]);
  ss = (r2[0] + r2[1]) + (r2[2] + r2[3]);
  float mu  = s * (1.f / (float)kD);
  float var = ss * (1.f / (float)kD) - mu * mu;
  float inv = rsqrtf(var + kLnEps);

  float4 gg = ((const float4*)lng)[tid];
  float4 bb = ((const float4*)lnb)[tid];
  float4 o;
  o.x = (g0 - mu) * inv * gg.x + bb.x;
  o.y = (g1 - mu) * inv * gg.y + bb.y;
  o.z = (g2 - mu) * inv * gg.z + bb.z;
  o.w = (g3 - mu) * inv * gg.w + bb.w;

  const int b = n >> 12, l = n & 4095;
  const int cc = tid * 4;
  size_t base = ((size_t)(b * 8192 + 2 * l)) * kD + cc;
  *(float4*)(OUT + base)      = o;
  *(float4*)(OUT + base + kD) = o;
}

// ---------------------------------------------------------------------------
extern "C" void kernel_launch(void* const* d_in, const int* in_sizes, int n_in,
                              void* d_out, int out_size, void* d_ws, size_t ws_size,
                              hipStream_t stream)
{
  (void)in_sizes; (void)n_in; (void)out_size; (void)ws_size;
  const float* x    = (const float*)d_in[0];
  const float* Wq   = (const float*)d_in[1];
  const float* Wk   = (const float*)d_in[2];
  const float* Wv   = (const float*)d_in[3];
  const float* Wo   = (const float*)d_in[4];
  const float* proj = (const float*)d_in[5];
  const float* lng  = (const float*)d_in[6];
  const float* lnb  = (const float*)d_in[7];
  float* out = (float*)d_out;

  // Workspace layout (MB offsets, total ~203.5 MB):
  //  0   xb    bf16 [8192,1024]
  //  16  WqT / 18 WkT / 20 WvT / 22 WoT  bf16 [1024,1024] transposed
  //  24  Qb    bf16 (alias: KVP f32 16 MB after favor-q)
  //  40  Kb    bf16 (alias: ATTN bf16 after favor-k)
  //  56  VT    bf16 [32 bh][64 d][4096 l]
  //  72  QF    bf16 [32,4096,256]  (alias: Y f32 after attn)
  //  136 KFT  bf16 [32 bh][256 m][4096 l]
  //  200 KSP  f32 [512][128]
  //  201 KVT  bf16 [32,80,256]
  //  203 projb bf16 [16,256,64]
  char* ws = (char*)d_ws;
  const size_t MB = 1024 * 1024;
  unsigned short* xb  = (unsigned short*)(ws);
  unsigned short* WqT = (unsigned short*)(ws + 16 * MB);
  unsigned short* WkT = (unsigned short*)(ws + 18 * MB);
  unsigned short* WvT = (unsigned short*)(ws + 20 * MB);
  unsigned short* WoT = (unsigned short*)(ws + 22 * MB);
  unsigned short* Qb  = (unsigned short*)(ws + 24 * MB);
  unsigned short* Kb  = (unsigned short*)(ws + 40 * MB);
  unsigned short* VT  = (unsigned short*)(ws + 56 * MB);
  unsigned short* QF  = (unsigned short*)(ws + 72 * MB);
  unsigned short* KFT = (unsigned short*)(ws + 136 * MB);
  float* KSP          = (float*)(ws + 200 * MB);
  unsigned short* KVT = (unsigned short*)(ws + 201 * MB);
  unsigned short* projb = (unsigned short*)(ws + 203 * MB);
  float* KVP          = (float*)(ws + 24 * MB);   // 16 MB, after Qb dead
  unsigned short* ATTN = Kb;                      // after favor-k consumed Kb
  float* Y            = (float*)(ws + 72 * MB);   // after QF consumed

  // 1) casts
  cast_bf16_kernel<<<(kN * kD) / 1024, 256, 0, stream>>>(x, xb);
  cast_bf16_kernel<<<(kH * kM * kDH) / 1024, 256, 0, stream>>>(proj, projb);
  transpose_cast_kernel<<<dim3(32, 32), 256, 0, stream>>>(Wq, WqT);
  transpose_cast_kernel<<<dim3(32, 32), 256, 0, stream>>>(Wk, WkT);
  transpose_cast_kernel<<<dim3(32, 32), 256, 0, stream>>>(Wv, WvT);
  transpose_cast_kernel<<<dim3(32, 32), 256, 0, stream>>>(Wo, WoT);

  // 2) projections via MFMA
  dim3 gg(8, 64);
  gemm_mfma<1><<<gg, 256, 0, stream>>>(xb, WkT, Kb, kScale);
  gemm_mfma<2><<<gg, 256, 0, stream>>>(xb, WvT, VT, 1.0f);   // per-head V^T
  gemm_mfma<1><<<gg, 256, 0, stream>>>(xb, WqT, Qb, kScale);

  // 3) FAVOR features via MFMA (K-side stored transposed), 64-row tiles
  favor_mfma<0><<<dim3(32, 64), 256, 0, stream>>>(Qb, projb, QF);
  favor_mfma<1><<<dim3(32, 64), 256, 0, stream>>>(Kb, projb, KFT);

  // 4) kv / k_sum via MFMA (8-way split over l), reduce to bf16 KVT'
  kv_mfma<<<dim3(32, 2, 8), 256, 0, stream>>>(KFT, VT, KVP, KSP);
  kv_reduce_kernel<<<32 * 80, 256, 0, stream>>>(KVP, KSP, KVT);

  // 5) MFMA attention read-out -> bf16 ATTN
  attn_mfma<<<dim3(32, 32), 256, 0, stream>>>(QF, KVT, ATTN);

  // 6) output projection (f32 out)
  gemm_mfma<0><<<gg, 256, 0, stream>>>(ATTN, WoT, Y, 1.0f);

  // 7) GELU + LayerNorm + 2x duplicate write
  gelu_ln_kernel<<<kN, 256, 0, stream>>>(Y, lng, lnb, out);
}